// Round 9
// baseline (281.665 us; speedup 1.0000x reference)
//
#include <hip/hip_runtime.h>
#include <stdint.h>

// Problem constants
constexpr int T = 2048;
constexpr int B = 8;
constexpr int C = 1024;
constexpr int H = 16;
constexpr int K = 31;
constexpr int BC = B * C;          // 8192 columns (b,c); stride between times
constexpr int HALO = K - 1;        // 30

// Tiling: block = 256 (b,c)-columns x 16 time steps.
// LDS tile rows are 256 floats = 1 KB -> every global_load_lds is one fully
// contiguous 1 KB (the only pattern the DMA coalescer handles cleanly, per
// R4-vs-R7 FETCH evidence), and every output store is one fully contiguous
// 1 KB nt store (fillBuffer's 6.5 TB/s pattern).
constexpr int TT = 16;             // time steps per block
constexpr int NR = TT + HALO;      // 46 LDS rows
constexpr int CW = 256;            // columns per block
constexpr int BLOCK = 256;
constexpr int TPT = 4;             // times per thread (wave w owns times 4w..4w+3)
constexpr int NTCH = T / TT;       // 128 time chunks
constexpr int NCOLG = BC / CW;     // 32 column groups
constexpr int NBLK = NTCH * NCOLG; // 4096 blocks; 46KB tile -> 3 blocks/CU

typedef const __attribute__((address_space(1))) uint32_t gas_u32;
typedef __attribute__((address_space(3))) uint32_t las_u32;
typedef float f32x4 __attribute__((ext_vector_type(4)));

// ---------------------------------------------------------------------------
// out[t,col] = sum_k ws[k] * x[t-30+k, col] + bias[c],  ws = softmax(w[head])
// Tile row r holds global time t0 - 30 + r (256 columns).
// Thread (wave w, lane l): channels col0+4l..+3, times t0+4w..+3 (d-major).
//
// R8 bug fixed here: with TT(16) < HALO(30), blocks with t0=16 (not just
// t0=0) have negative-time rows (0..13) that the DMA correctly skips but
// R8 never zero-filled -> stale LDS read. Zero-fill now covers all rows
// j < HALO - t0 whenever t0 < HALO.
// ---------------------------------------------------------------------------
__global__ __launch_bounds__(BLOCK, 3) void lconv_tbc_kernel(
        const float* __restrict__ x,
        const float* __restrict__ w,
        const float* __restrict__ bias,
        float* __restrict__ out) {
    __shared__ float tile[NR][CW];   // 46 KiB

    const int tid = threadIdx.x;
    const int wid = tid >> 6;
    const int lane = tid & 63;
    // tch-major: consecutive blocks walk time in the same columns -> 30/46
    // halo rows re-read by the next block are L2-resident on the same XCD.
    const int tch = blockIdx.x & (NTCH - 1);
    const int colg = blockIdx.x >> 7;           // log2(NTCH) = 7
    const int t0 = tch * TT;
    const int col0 = colg * CW;
    const int cb = col0 & (C - 1);              // channel base (mult of 256)
    const int c4 = 4 * lane;                    // thread's channel offset
    const int h = (cb + c4) >> 6;               // per-lane head (4 per wave)

    // --- Tap + bias loads FIRST so their waitcnt doesn't drain the DMA ---
    float wv[K];
    #pragma unroll
    for (int k = 0; k < K; ++k) wv[k] = w[h * K + k];
    const f32x4 bi = *(const f32x4*)&bias[cb + c4];

    // --- DMA: wave w stages rows w, w+4, ... Each instr: 1 KB contiguous
    // global -> LDS dest uniform base + lane*16 (tile[r][4l] = x row col 4l).
    const float* src = x + (t0 - HALO) * BC + col0 + c4;
    #pragma unroll
    for (int i = 0; i < 12; ++i) {
        const int r = wid + 4 * i;
        if (r < NR && t0 - HALO + r >= 0)
            __builtin_amdgcn_global_load_lds((gas_u32*)(src + r * BC),
                                             (las_u32*)&tile[r][0], 16, 0, 0);
    }
    // Causal zero padding for ALL rows with negative global time. With
    // TT < HALO this applies to t0 = 0 (rows 0..29) AND t0 = 16 (rows 0..13).
    if (t0 < HALO) {
        const int nz = HALO - t0;               // rows 0..nz-1 are t < 0
        for (int j = 0; j < nz; ++j) tile[j][tid] = 0.0f;
    }

    // --- Per-lane softmax of this lane's head taps (overlaps DMA drain) ---
    float m = -1e30f;
    #pragma unroll
    for (int k = 0; k < K; ++k) m = fmaxf(m, wv[k]);
    float s = 0.0f;
    #pragma unroll
    for (int k = 0; k < K; ++k) {
        wv[k] = __expf(wv[k] - m);
        s += wv[k];
    }
    const float inv = 1.0f / s;
    #pragma unroll
    for (int k = 0; k < K; ++k) wv[k] *= inv;

    __syncthreads();   // one drain per block; 3 resident blocks/CU overlap it

    // --- d-major: 34 ds_read_b128, each row consumed then dead (VGPR stays
    // low by construction -> no pressure-driven scheduler war). Output time
    // tau = t0+4*wid+u uses tile row 4*wid+u+k with weight wv[k]; j = u+k.
    f32x4 acc[TPT];
    #pragma unroll
    for (int u = 0; u < TPT; ++u) acc[u] = bi;

    const float* trow = &tile[TPT * wid][c4];
    #pragma unroll
    for (int j = 0; j < TPT + K - 1; ++j) {      // 34 rows
        const f32x4 r = *(const f32x4*)(trow + j * CW);
        #pragma unroll
        for (int u = 0; u < TPT; ++u) {
            const int k = j - u;
            if (k >= 0 && k < K) {
                acc[u].x = fmaf(wv[k], r.x, acc[u].x);
                acc[u].y = fmaf(wv[k], r.y, acc[u].y);
                acc[u].z = fmaf(wv[k], r.z, acc[u].z);
                acc[u].w = fmaf(wv[k], r.w, acc[u].w);
            }
        }
    }

    // --- 4 stores, each one fully contiguous 1 KB per wave ---
    const int obase = (t0 + TPT * wid) * BC + col0 + c4;
    #pragma unroll
    for (int u = 0; u < TPT; ++u)
        __builtin_nontemporal_store(acc[u], (f32x4*)(out + obase + u * BC));
}

extern "C" void kernel_launch(void* const* d_in, const int* in_sizes, int n_in,
                              void* d_out, int out_size, void* d_ws, size_t ws_size,
                              hipStream_t stream) {
    const float* x = (const float*)d_in[0];      // [T, B, C]
    const float* w = (const float*)d_in[1];      // [H, 1, K]
    const float* bias = (const float*)d_in[2];   // [C]
    float* out = (float*)d_out;                  // [T, B, C]

    lconv_tbc_kernel<<<dim3(NBLK), dim3(BLOCK), 0, stream>>>(x, w, bias, out);
}

// Round 10
// 272.899 us; speedup vs baseline: 1.0321x; 1.0321x over previous
//
#include <hip/hip_runtime.h>
#include <stdint.h>

// Problem constants
constexpr int T = 2048;
constexpr int B = 8;
constexpr int C = 1024;
constexpr int H = 16;
constexpr int K = 31;
constexpr int BC = B * C;          // 8192 columns (b,c); stride between times
constexpr int HALO = K - 1;        // 30

// Tiling: block = 256 (b,c)-columns x 16 time steps.
constexpr int TT = 16;             // time steps per block
constexpr int NR = TT + HALO;      // 46 LDS rows
constexpr int CW = 256;            // columns per block
constexpr int BLOCK = 256;
constexpr int TPT = 4;             // times per thread (wave w owns times 4w..4w+3)
constexpr int NTCH = T / TT;       // 128 time chunks
constexpr int NCOLG = BC / CW;     // 32 column groups
constexpr int NBLK = NTCH * NCOLG; // 4096 blocks; 46KB tile -> 3 blocks/CU

typedef const __attribute__((address_space(1))) uint32_t gas_u32;
typedef __attribute__((address_space(3))) uint32_t las_u32;
typedef float f32x4 __attribute__((ext_vector_type(4)));

// ---------------------------------------------------------------------------
// out[t,col] = sum_k ws[k] * x[t-30+k, col] + bias[c],  ws = softmax(w[head])
// Tile row r holds global time t0 - 30 + r (256 columns).
// Thread (wave w, lane l): channels col0+4l..+3, times t0+4w..+3 (d-major).
//
// R9 lesson encoded here: NEVER use __builtin_nontemporal_store on a vector
// type — clang scalarizes it into 4 interleaved dword-nt stores (4B/lane at
// stride 16B = 1/4-coverage of every 64B sector); nt+partial-sector forces
// HBM read-modify-write => 10.5x WRITE_SIZE and ~8x phantom FETCH (R7/R9).
// Plain f32x4 stores emit one global_store_dwordx4: full-wave-contiguous 1KB.
// ---------------------------------------------------------------------------
__global__ __launch_bounds__(BLOCK, 3) void lconv_tbc_kernel(
        const float* __restrict__ x,
        const float* __restrict__ w,
        const float* __restrict__ bias,
        float* __restrict__ out) {
    __shared__ float tile[NR][CW];   // 46 KiB

    const int tid = threadIdx.x;
    const int wid = tid >> 6;
    const int lane = tid & 63;
    // tch-major: consecutive blocks walk time in the same columns.
    const int tch = blockIdx.x & (NTCH - 1);
    const int colg = blockIdx.x >> 7;           // log2(NTCH) = 7
    const int t0 = tch * TT;
    const int col0 = colg * CW;
    const int cb = col0 & (C - 1);              // channel base (mult of 256)
    const int c4 = 4 * lane;                    // thread's channel offset
    const int h = (cb + c4) >> 6;               // per-lane head (4 per wave)

    // --- Tap + bias loads FIRST so their waitcnt doesn't drain the DMA ---
    float wv[K];
    #pragma unroll
    for (int k = 0; k < K; ++k) wv[k] = w[h * K + k];
    const f32x4 bi = *(const f32x4*)&bias[cb + c4];

    // --- DMA: wave w stages rows w, w+4, ... Each instr: 1 KB contiguous
    // global -> LDS dest uniform base + lane*16 (tile[r][4l] = x row col 4l).
    const float* src = x + (t0 - HALO) * BC + col0 + c4;
    #pragma unroll
    for (int i = 0; i < 12; ++i) {
        const int r = wid + 4 * i;
        if (r < NR && t0 - HALO + r >= 0)
            __builtin_amdgcn_global_load_lds((gas_u32*)(src + r * BC),
                                             (las_u32*)&tile[r][0], 16, 0, 0);
    }
    // Causal zero padding for ALL rows with negative global time (t0 < HALO
    // covers both t0 = 0, rows 0..29, and t0 = 16, rows 0..13).
    if (t0 < HALO) {
        const int nz = HALO - t0;               // rows 0..nz-1 are t < 0
        for (int j = 0; j < nz; ++j) tile[j][tid] = 0.0f;
    }

    // --- Per-lane softmax of this lane's head taps (overlaps DMA drain) ---
    float m = -1e30f;
    #pragma unroll
    for (int k = 0; k < K; ++k) m = fmaxf(m, wv[k]);
    float s = 0.0f;
    #pragma unroll
    for (int k = 0; k < K; ++k) {
        wv[k] = __expf(wv[k] - m);
        s += wv[k];
    }
    const float inv = 1.0f / s;
    #pragma unroll
    for (int k = 0; k < K; ++k) wv[k] *= inv;

    __syncthreads();   // one drain per block; 3 resident blocks/CU overlap it

    // --- d-major: 34 ds_read_b128, each row consumed then dead. Output time
    // tau = t0+4*wid+u uses tile row 4*wid+u+k with weight wv[k]; j = u+k.
    f32x4 acc[TPT];
    #pragma unroll
    for (int u = 0; u < TPT; ++u) acc[u] = bi;

    const float* trow = &tile[TPT * wid][c4];
    #pragma unroll
    for (int j = 0; j < TPT + K - 1; ++j) {      // 34 rows
        const f32x4 r = *(const f32x4*)(trow + j * CW);
        #pragma unroll
        for (int u = 0; u < TPT; ++u) {
            const int k = j - u;
            if (k >= 0 && k < K) {
                acc[u].x = fmaf(wv[k], r.x, acc[u].x);
                acc[u].y = fmaf(wv[k], r.y, acc[u].y);
                acc[u].z = fmaf(wv[k], r.z, acc[u].z);
                acc[u].w = fmaf(wv[k], r.w, acc[u].w);
            }
        }
    }

    // --- 4 stores, each one global_store_dwordx4: fully contiguous 1 KB
    // per wave (plain store, NOT the vector-nt builtin — see header note).
    const int obase = (t0 + TPT * wid) * BC + col0 + c4;
    #pragma unroll
    for (int u = 0; u < TPT; ++u)
        *(f32x4*)(out + obase + u * BC) = acc[u];
}

extern "C" void kernel_launch(void* const* d_in, const int* in_sizes, int n_in,
                              void* d_out, int out_size, void* d_ws, size_t ws_size,
                              hipStream_t stream) {
    const float* x = (const float*)d_in[0];      // [T, B, C]
    const float* w = (const float*)d_in[1];      // [H, 1, K]
    const float* bias = (const float*)d_in[2];   // [C]
    float* out = (float*)d_out;                  // [T, B, C]

    lconv_tbc_kernel<<<dim3(NBLK), dim3(BLOCK), 0, stream>>>(x, w, bias, out);
}

// Round 11
// 28.002 us; speedup vs baseline: 10.0589x; 9.7458x over previous
//
#include <hip/hip_runtime.h>
#include <stdint.h>

// Problem constants
constexpr int T = 2048;
constexpr int B = 8;
constexpr int C = 1024;
constexpr int H = 16;
constexpr int K = 31;
constexpr int BC = B * C;            // 8192, stride between time steps

// Tiling (R3 skeleton — the fastest clean-traffic structure so far)
constexpr int TT = 32;               // outputs per thread
constexpr int NB = K - 1 + TT;       // 61 window registers
constexpr int BLOCK = 256;
constexpr int BLK_PER_CHUNK = BC / BLOCK;    // 32
constexpr int NCHUNK = T / TT;               // 64
constexpr int NBLK = BLK_PER_CHUNK * NCHUNK; // 2048

// ---------------------------------------------------------------------------
// out[t,b,c] = sum_{d=0..K-1} wr[d] * x[t-d, b, c] + bias[c]
// wr[d] = softmax(w[h])[K-1-d]  (head h is wave-uniform).
//
// Structure: the 61-deep load window is issued as 61 asm-volatile
// global_load_dword with distinct "=v" outputs. Volatile asm pins issue
// order and the allocator MUST keep all destinations live to their
// consumers -> the pressure-driven load-sinking that collapsed R2/R3/R5/R6
// (VGPR 40-64, serial load->use chains) is impossible. LLVM's exact
// per-register vmcnt tracking then emits counted s_waitcnt vmcnt(N) as the
// FMA ladder walks buf[] oldest-first: ONE latency exposure per thread.
//
// Softmax is register-lean on purpose (taps in SGPRs, exp recomputed, ~3
// VGPRs) and sits between load-issue and the ladder to fill the shadow.
// Stores: scalar nontemporal (proven WRITE_SIZE == 65536 KB exactly).
// ---------------------------------------------------------------------------
__global__ __launch_bounds__(BLOCK) void lconv_tbc_kernel(
        const float* __restrict__ x,
        const float* __restrict__ w,
        const float* __restrict__ bias,
        float* __restrict__ out) {
    const int tid = threadIdx.x;
    const int cb = blockIdx.x & (BLK_PER_CHUNK - 1);   // bc slice (fastest)
    const int chunk = blockIdx.x / BLK_PER_CHUNK;      // time chunk
    const int bc = cb * BLOCK + tid;                   // [0, BC)
    const int c = bc & (C - 1);
    const int h = __builtin_amdgcn_readfirstlane(c >> 6);  // wave-uniform head

    const int t0 = chunk * TT;
    const float* col = x + bc;          // per-lane column base

    // bias load first (oldest in vmcnt queue, drains before the window).
    const float bi = bias[c];

    // ---- Issue the entire 61-deep window: pinned-order asm loads ----
    float buf[NB];
    if (chunk == 0) {
        #pragma unroll
        for (int j = 0; j < K - 1; ++j) buf[j] = 0.0f;
        #pragma unroll
        for (int j = K - 1; j < NB; ++j) {
            const float* a = col + (t0 + (j - (K - 1))) * BC;
            asm volatile("global_load_dword %0, %1, off"
                         : "=v"(buf[j]) : "v"(a));
        }
    } else {
        #pragma unroll
        for (int j = 0; j < NB; ++j) {
            const float* a = col + (t0 - (K - 1) + j) * BC;
            asm volatile("global_load_dword %0, %1, off"
                         : "=v"(buf[j]) : "v"(a));
        }
    }

    // ---- Register-lean softmax in the load shadow ----
    // Taps are wave-uniform -> SGPRs via s_load; exp recomputed (62 v_exp,
    // ~250 cy of VALU that fills the memory latency window).
    float tap[K];
    #pragma unroll
    for (int k = 0; k < K; ++k)
        tap[k] = __uint_as_float(__builtin_amdgcn_readfirstlane(
            __float_as_uint(w[h * K + k])));
    float m = tap[0];
    #pragma unroll
    for (int k = 1; k < K; ++k) m = fmaxf(m, tap[k]);
    float s = 0.0f;
    #pragma unroll
    for (int k = 0; k < K; ++k) s += __expf(tap[k] - m);
    const float inv = 1.0f / s;
    float wr[K];   // reversed, wave-uniform -> SGPRs
    #pragma unroll
    for (int d = 0; d < K; ++d)
        wr[d] = __uint_as_float(__builtin_amdgcn_readfirstlane(
            __float_as_uint(__expf(tap[K - 1 - d] - m) * inv)));

    // ---- 32 outputs x 31 FMAs; buf consumed oldest-first so the
    // compiler's exact vmcnt tracking drains the queue incrementally. ----
    const int base = t0 * BC + bc;      // element index fits int (max 16.8M)
    #pragma unroll
    for (int u = 0; u < TT; ++u) {
        float acc = bi;
        #pragma unroll
        for (int d = 0; d < K; ++d)
            acc = fmaf(wr[d], buf[K - 1 + u - d], acc);
        __builtin_nontemporal_store(acc, &out[base + u * BC]);
    }
}

extern "C" void kernel_launch(void* const* d_in, const int* in_sizes, int n_in,
                              void* d_out, int out_size, void* d_ws, size_t ws_size,
                              hipStream_t stream) {
    const float* x = (const float*)d_in[0];      // [T, B, C]
    const float* w = (const float*)d_in[1];      // [H, 1, K]
    const float* bias = (const float*)d_in[2];   // [C]
    float* out = (float*)d_out;                  // [T, B, C]

    lconv_tbc_kernel<<<dim3(NBLK), dim3(BLOCK), 0, stream>>>(x, w, bias, out);
}